// Round 14
// baseline (142.244 us; speedup 1.0000x reference)
//
#include <hip/hip_runtime.h>

#define B_ 32
#define C_ 64
#define N_ 1024
#define T_ 64

typedef __attribute__((ext_vector_type(8))) _Float16 half8;   // 8 f16 = 4 VGPR
typedef __attribute__((ext_vector_type(4))) _Float16 half4;
typedef __attribute__((ext_vector_type(4))) float f32x4;

// ---------------------------------------------------------------------------
// K1 (R28): ONE change vs R25 — x loads are CACHED, not NT.
// Evidence: harness fill kernels sustain 6.8-6.9 TB/s pure WRITES; K1 reads
// at only 5.85 TB/s. R26 showed the NT path throttles dwordx4 STORES by 18us;
// suspect the NT (sc1/nt) READ path similarly under-delivers vs cached. The
// prior session's "95% of read ceiling" probe likely used NT loads itself —
// a self-referential ceiling (rule #10). A pure stream doesn't need L2
// protection (x churns L2 but nothing L2-resident is needed until K2).
// Predict: K1 87.5 -> 80-83 if NT was throttling, total ~109-113.
// Neutral/regression -> K1 floor confirmed; declare ROOFLINE next round.
// ---------------------------------------------------------------------------
__global__ __launch_bounds__(256) void k_q(const float* __restrict__ x,
                                           const float* __restrict__ alpha,
                                           _Float16* __restrict__ q_h) {
    const int bid = blockIdx.x;
    const int s1  = (bid & 7) * 256 + (bid >> 3);   // bijective, 2048%8==0
    const int b   = s1 >> 6;
    const int n0  = (s1 & 63) * 16;
    const int tid = threadIdx.x;

    const f32x4* xb = (const f32x4*)(x + (size_t)b * C_ * N_ * T_
                                       + (size_t)n0 * T_);
    f32x4 acc = {0.f, 0.f, 0.f, 0.f};
#pragma unroll 4
    for (int c = 0; c < C_; ++c) {
        f32x4 v = xb[(size_t)c * (N_ * T_ / 4) + tid];   // CACHED (was NT)
        const float ac = alpha[c];
        acc[0] += ac * v[0]; acc[1] += ac * v[1];
        acc[2] += ac * v[2]; acc[3] += ac * v[3];
    }

    half4 h;
#pragma unroll
    for (int j = 0; j < 4; ++j) h[j] = (_Float16)acc[j];   // RTNE cvt
    *(half4*)(q_h + ((size_t)b * N_ + n0) * T_ + (size_t)tid * 4) = h;
}

// ---------------------------------------------------------------------------
// K2 (R25 body, unchanged — best known: 116.79us total).
// bst-first loads, W direct-from-global split-precision qw MFMA, ONE head
// barrier, 4-tile store-streaming loop with LDS-only barriers, red[2] dbuf,
// cached dwordx4 stores (R26: NT stores -18.5us).
// ---------------------------------------------------------------------------
__global__ __launch_bounds__(512, 4) void k_scores_softmax(
        const _Float16* __restrict__ q_h,
        const float* __restrict__ W,
        float* __restrict__ out) {
    const int bid = blockIdx.x;
    const int s   = (bid & 7) * 64 + (bid >> 3);    // bijective, 512%8==0
    const int b   = s >> 4;                         // same b<->XCD map as K1
    const int n0  = (s & 15) * 64;                  // 64-row tile base
    const int tid  = threadIdx.x;
    const int w    = tid >> 6;                      // wave 0..7 -> cols w*128
    const int lane = tid & 63;
    const int lr   = lane & 15;
    const int lk   = lane >> 4;

    __shared__ _Float16 qwh[64][72];                // 9 KB f16 qw tile
    __shared__ float red[2][16][8];                 // 1 KB, double-buffered

    // ---- 1) bst loads FIRST: 16 tile-independent frags, longest latency ----
    half8 bst0[8], bst1[8];                         // 64 VGPR, live whole loop
    const size_t cb0 = ((size_t)b * N_ + w * 128 + lr) * T_ + lk * 8;
#pragma unroll
    for (int cf = 0; cf < 8; ++cf) {
        bst0[cf] = *(const half8*)(q_h + cb0 + (size_t)cf * 16 * T_);
        bst1[cf] = *(const half8*)(q_h + cb0 + (size_t)cf * 16 * T_ + 32);
    }

    // ---- 2) W direct per-lane (no LDS round-trip; L2/L3-hot) ----
    const int tc  = w & 3;
    const int tr0 = (w >> 2) * 2;
    float wv0[8], wv1[8];
#pragma unroll
    for (int j = 0; j < 8; ++j) {
        wv0[j] = W[(lk * 8 + j) * T_ + tc * 16 + lr];
        wv1[j] = W[(lk * 8 + 32 + j) * T_ + tc * 16 + lr];
    }
    half8 bh0, bh1, bl0, bl1;
#pragma unroll
    for (int j = 0; j < 8; ++j) {
        const _Float16 h0 = (_Float16)wv0[j];
        const _Float16 h1 = (_Float16)wv1[j];
        bh0[j] = h0; bl0[j] = (_Float16)(wv0[j] - (float)h0);
        bh1[j] = h1; bl1[j] = (_Float16)(wv1[j] - (float)h1);
    }

    // ---- 3) qw (2 row-blocks) = q @ W, split-precision, -> qwh LDS ----
#pragma unroll
    for (int i = 0; i < 2; ++i) {
        const int tr = tr0 + i;
        const size_t ar = ((size_t)b * N_ + n0 + tr * 16 + lr) * T_ + lk * 8;
        half8 a0 = *(const half8*)(q_h + ar);        // k = lk*8 .. +7
        half8 a1 = *(const half8*)(q_h + ar + 32);
        f32x4 a = {0.f, 0.f, 0.f, 0.f};
        a = __builtin_amdgcn_mfma_f32_16x16x32_f16(a0, bh0, a, 0, 0, 0);
        a = __builtin_amdgcn_mfma_f32_16x16x32_f16(a1, bh1, a, 0, 0, 0);
        a = __builtin_amdgcn_mfma_f32_16x16x32_f16(a0, bl0, a, 0, 0, 0);
        a = __builtin_amdgcn_mfma_f32_16x16x32_f16(a1, bl1, a, 0, 0, 0);
        // C layout: col = lr, row = lk*4 + r
#pragma unroll
        for (int r = 0; r < 4; ++r)
            qwh[tr * 16 + lk * 4 + r][tc * 16 + lr] = (_Float16)a[r];
    }
    __syncthreads();                                // ONE head barrier

    float* const obase = out + ((size_t)b * N_ + n0 + lr) * N_ + w * 128 + lk * 4;

    // ---- 4 row-tiles; tile g's stores drain under tile g+1's compute ----
#pragma unroll 1
    for (int g = 0; g < 4; ++g) {
        half8 af0 = *(const half8*)&qwh[g * 16 + lr][lk * 8];
        half8 af1 = *(const half8*)&qwh[g * 16 + lr][lk * 8 + 32];

        f32x4 acc[8];
#pragma unroll
        for (int cf = 0; cf < 8; ++cf) {
            // swapped operands: lane owns out row n0+g*16+lr,
            // reg r = col w*128+cf*16+lk*4+r (4 consecutive floats)
            f32x4 a = {0.f, 0.f, 0.f, 0.f};
            a = __builtin_amdgcn_mfma_f32_16x16x32_f16(bst0[cf], af0, a, 0, 0, 0);
            a = __builtin_amdgcn_mfma_f32_16x16x32_f16(bst1[cf], af1, a, 0, 0, 0);
            acc[cf] = a;
        }

        // ---- max-free softmax for these 16 rows ----
        float ssum = 0.f;
#pragma unroll
        for (int cf = 0; cf < 8; ++cf) {
#pragma unroll
            for (int r = 0; r < 4; ++r) {
                float e = __expf(acc[cf][r]);
                acc[cf][r] = e;
                ssum += e;
            }
        }
        ssum += __shfl_xor(ssum, 16);               // sum across lk group
        ssum += __shfl_xor(ssum, 32);
        if (lane < 16) red[g & 1][lr][w] = ssum;

        // LDS-ONLY barrier: lgkmcnt drained, vmcnt NOT -> prior tile's global
        // stores keep draining under this barrier and the next tile's compute.
        asm volatile("s_waitcnt lgkmcnt(0)" ::: "memory");
        __builtin_amdgcn_s_barrier();
        asm volatile("" ::: "memory");

        f32x4 p0 = *(f32x4*)&red[g & 1][lr][0];
        f32x4 p1 = *(f32x4*)&red[g & 1][lr][4];
        const float inv = 1.0f / (p0[0] + p0[1] + p0[2] + p0[3] +
                                  p1[0] + p1[1] + p1[2] + p1[3]);
        f32x4* orow = (f32x4*)(obase + (size_t)g * 16 * N_);
#pragma unroll
        for (int cf = 0; cf < 8; ++cf) {
            f32x4 v = acc[cf];
            v[0] *= inv; v[1] *= inv; v[2] *= inv; v[3] *= inv;
            orow[cf * 4] = v;                       // cached dwordx4
        }
    }
}

// ---------------------------------------------------------------------------
extern "C" void kernel_launch(void* const* d_in, const int* in_sizes, int n_in,
                              void* d_out, int out_size, void* d_ws, size_t ws_size,
                              hipStream_t stream) {
    const float* x     = (const float*)d_in[0];
    const float* W     = (const float*)d_in[1];
    const float* alpha = (const float*)d_in[2];
    float* out = (float*)d_out;

    _Float16* q_h = (_Float16*)d_ws;                // [B,N,T] f16, 4 MB

    k_q<<<2048, 256, 0, stream>>>(x, alpha, q_h);
    k_scores_softmax<<<512, 512, 0, stream>>>(q_h, W, out);
}

// Round 15
// 116.774 us; speedup vs baseline: 1.2181x; 1.2181x over previous
//
#include <hip/hip_runtime.h>

#define B_ 32
#define C_ 64
#define N_ 1024
#define T_ 64

typedef __attribute__((ext_vector_type(8))) _Float16 half8;   // 8 f16 = 4 VGPR
typedef __attribute__((ext_vector_type(4))) _Float16 half4;
typedef __attribute__((ext_vector_type(4))) float f32x4;

// ---------------------------------------------------------------------------
// R29 = R25 EXACT REVERT (best known: 116.79us). R28 proved NT x-loads are
// essential (cached: +25.5us, L2 thrash at 3.6 TB/s). Session ledger:
//  K1 ~87.5us NT stream (A/B-confirmed both directions) | K2 drain 17.2us at
//  write ceiling (R18/R20 measured) | K2 head ~12us (6 attacks, all null/neg)
//  | fusion x3: -60..-160us. Residual ~7us over the ~109us component bound
//  survived 12 falsification attempts -> structural floor of this approach.
// ---------------------------------------------------------------------------
__global__ __launch_bounds__(256) void k_q(const float* __restrict__ x,
                                           const float* __restrict__ alpha,
                                           _Float16* __restrict__ q_h) {
    const int bid = blockIdx.x;
    const int s1  = (bid & 7) * 256 + (bid >> 3);   // bijective, 2048%8==0
    const int b   = s1 >> 6;
    const int n0  = (s1 & 63) * 16;
    const int tid = threadIdx.x;

    const f32x4* xb = (const f32x4*)(x + (size_t)b * C_ * N_ * T_
                                       + (size_t)n0 * T_);
    f32x4 acc = {0.f, 0.f, 0.f, 0.f};
#pragma unroll 4
    for (int c = 0; c < C_; ++c) {
        f32x4 v = __builtin_nontemporal_load(&xb[(size_t)c * (N_ * T_ / 4) + tid]);
        const float ac = alpha[c];
        acc[0] += ac * v[0]; acc[1] += ac * v[1];
        acc[2] += ac * v[2]; acc[3] += ac * v[3];
    }

    half4 h;
#pragma unroll
    for (int j = 0; j < 4; ++j) h[j] = (_Float16)acc[j];   // RTNE cvt
    *(half4*)(q_h + ((size_t)b * N_ + n0) * T_ + (size_t)tid * 4) = h;
}

// ---------------------------------------------------------------------------
// K2 (R25 body): bst-first loads, W direct-from-global split-precision qw
// MFMA, ONE head barrier, 4-tile store-streaming loop with LDS-only barriers
// (vmcnt NOT drained -> stores overlap next tile's compute), red[2] dbuf,
// cached dwordx4 stores (R26: NT stores -18.5us).
// ---------------------------------------------------------------------------
__global__ __launch_bounds__(512, 4) void k_scores_softmax(
        const _Float16* __restrict__ q_h,
        const float* __restrict__ W,
        float* __restrict__ out) {
    const int bid = blockIdx.x;
    const int s   = (bid & 7) * 64 + (bid >> 3);    // bijective, 512%8==0
    const int b   = s >> 4;                         // same b<->XCD map as K1
    const int n0  = (s & 15) * 64;                  // 64-row tile base
    const int tid  = threadIdx.x;
    const int w    = tid >> 6;                      // wave 0..7 -> cols w*128
    const int lane = tid & 63;
    const int lr   = lane & 15;
    const int lk   = lane >> 4;

    __shared__ _Float16 qwh[64][72];                // 9 KB f16 qw tile
    __shared__ float red[2][16][8];                 // 1 KB, double-buffered

    // ---- 1) bst loads FIRST: 16 tile-independent frags, longest latency ----
    half8 bst0[8], bst1[8];                         // 64 VGPR, live whole loop
    const size_t cb0 = ((size_t)b * N_ + w * 128 + lr) * T_ + lk * 8;
#pragma unroll
    for (int cf = 0; cf < 8; ++cf) {
        bst0[cf] = *(const half8*)(q_h + cb0 + (size_t)cf * 16 * T_);
        bst1[cf] = *(const half8*)(q_h + cb0 + (size_t)cf * 16 * T_ + 32);
    }

    // ---- 2) W direct per-lane (no LDS round-trip; L2/L3-hot) ----
    const int tc  = w & 3;
    const int tr0 = (w >> 2) * 2;
    float wv0[8], wv1[8];
#pragma unroll
    for (int j = 0; j < 8; ++j) {
        wv0[j] = W[(lk * 8 + j) * T_ + tc * 16 + lr];
        wv1[j] = W[(lk * 8 + 32 + j) * T_ + tc * 16 + lr];
    }
    half8 bh0, bh1, bl0, bl1;
#pragma unroll
    for (int j = 0; j < 8; ++j) {
        const _Float16 h0 = (_Float16)wv0[j];
        const _Float16 h1 = (_Float16)wv1[j];
        bh0[j] = h0; bl0[j] = (_Float16)(wv0[j] - (float)h0);
        bh1[j] = h1; bl1[j] = (_Float16)(wv1[j] - (float)h1);
    }

    // ---- 3) qw (2 row-blocks) = q @ W, split-precision, -> qwh LDS ----
#pragma unroll
    for (int i = 0; i < 2; ++i) {
        const int tr = tr0 + i;
        const size_t ar = ((size_t)b * N_ + n0 + tr * 16 + lr) * T_ + lk * 8;
        half8 a0 = *(const half8*)(q_h + ar);        // k = lk*8 .. +7
        half8 a1 = *(const half8*)(q_h + ar + 32);
        f32x4 a = {0.f, 0.f, 0.f, 0.f};
        a = __builtin_amdgcn_mfma_f32_16x16x32_f16(a0, bh0, a, 0, 0, 0);
        a = __builtin_amdgcn_mfma_f32_16x16x32_f16(a1, bh1, a, 0, 0, 0);
        a = __builtin_amdgcn_mfma_f32_16x16x32_f16(a0, bl0, a, 0, 0, 0);
        a = __builtin_amdgcn_mfma_f32_16x16x32_f16(a1, bl1, a, 0, 0, 0);
        // C layout: col = lr, row = lk*4 + r
#pragma unroll
        for (int r = 0; r < 4; ++r)
            qwh[tr * 16 + lk * 4 + r][tc * 16 + lr] = (_Float16)a[r];
    }
    __syncthreads();                                // ONE head barrier

    float* const obase = out + ((size_t)b * N_ + n0 + lr) * N_ + w * 128 + lk * 4;

    // ---- 4 row-tiles; tile g's stores drain under tile g+1's compute ----
#pragma unroll 1
    for (int g = 0; g < 4; ++g) {
        half8 af0 = *(const half8*)&qwh[g * 16 + lr][lk * 8];
        half8 af1 = *(const half8*)&qwh[g * 16 + lr][lk * 8 + 32];

        f32x4 acc[8];
#pragma unroll
        for (int cf = 0; cf < 8; ++cf) {
            // swapped operands: lane owns out row n0+g*16+lr,
            // reg r = col w*128+cf*16+lk*4+r (4 consecutive floats)
            f32x4 a = {0.f, 0.f, 0.f, 0.f};
            a = __builtin_amdgcn_mfma_f32_16x16x32_f16(bst0[cf], af0, a, 0, 0, 0);
            a = __builtin_amdgcn_mfma_f32_16x16x32_f16(bst1[cf], af1, a, 0, 0, 0);
            acc[cf] = a;
        }

        // ---- max-free softmax for these 16 rows ----
        float ssum = 0.f;
#pragma unroll
        for (int cf = 0; cf < 8; ++cf) {
#pragma unroll
            for (int r = 0; r < 4; ++r) {
                float e = __expf(acc[cf][r]);
                acc[cf][r] = e;
                ssum += e;
            }
        }
        ssum += __shfl_xor(ssum, 16);               // sum across lk group
        ssum += __shfl_xor(ssum, 32);
        if (lane < 16) red[g & 1][lr][w] = ssum;

        // LDS-ONLY barrier: lgkmcnt drained, vmcnt NOT -> prior tile's global
        // stores keep draining under this barrier and the next tile's compute.
        asm volatile("s_waitcnt lgkmcnt(0)" ::: "memory");
        __builtin_amdgcn_s_barrier();
        asm volatile("" ::: "memory");

        f32x4 p0 = *(f32x4*)&red[g & 1][lr][0];
        f32x4 p1 = *(f32x4*)&red[g & 1][lr][4];
        const float inv = 1.0f / (p0[0] + p0[1] + p0[2] + p0[3] +
                                  p1[0] + p1[1] + p1[2] + p1[3]);
        f32x4* orow = (f32x4*)(obase + (size_t)g * 16 * N_);
#pragma unroll
        for (int cf = 0; cf < 8; ++cf) {
            f32x4 v = acc[cf];
            v[0] *= inv; v[1] *= inv; v[2] *= inv; v[3] *= inv;
            orow[cf * 4] = v;                       // cached dwordx4
        }
    }
}

// ---------------------------------------------------------------------------
extern "C" void kernel_launch(void* const* d_in, const int* in_sizes, int n_in,
                              void* d_out, int out_size, void* d_ws, size_t ws_size,
                              hipStream_t stream) {
    const float* x     = (const float*)d_in[0];
    const float* W     = (const float*)d_in[1];
    const float* alpha = (const float*)d_in[2];
    float* out = (float*)d_out;

    _Float16* q_h = (_Float16*)d_ws;                // [B,N,T] f16, 4 MB

    k_q<<<2048, 256, 0, stream>>>(x, alpha, q_h);
    k_scores_softmax<<<512, 512, 0, stream>>>(q_h, W, out);
}